// Round 24
// baseline (113.103 us; speedup 1.0000x reference)
//
#include <hip/hip_runtime.h>
#include <math.h>

// Problem constants
#define N_SP 96      // NV + NH
#define D_EMB 32
#define H_MLP 32
#define NPAIR 9216   // N*N
#define NBT 512      // B*T
#define BROWS 16     // rows per block (main: 6 blocks per (b,t))

// float workspace offsets (floats)
#define WS_F_EMBI  0         // 96*32 (includes +b1)
#define WS_F_EMBJT 3072      // 32*97 (transposed [u][j], row stride 97)
#define WS_F_ALPHA 6176      // 96
#define WS_F_WG4   6272      // 9216*4
#define WS_F_WG1   43136     // 9216

typedef __attribute__((ext_vector_type(8))) short bf16x8;
typedef __attribute__((ext_vector_type(4))) float f32x4;
typedef __attribute__((ext_vector_type(4))) unsigned u32x4;

__device__ __forceinline__ float gelu_fast(float x){
  float x2 = x * x;
  float z  = x * fmaf(x2, -0.1029438824f, -2.3022077325f);
  float e  = __builtin_amdgcn_exp2f(z);
  return x * __builtin_amdgcn_rcpf(1.0f + e);
}

__device__ __forceinline__ unsigned short f2bf(float f){
  unsigned u = __builtin_bit_cast(unsigned, f);
  unsigned r = (u + 0x7FFFu + ((u >> 16) & 1u)) >> 16;
  return (unsigned short)r;
}
__device__ __forceinline__ float bf2f(unsigned short s){
  unsigned u = ((unsigned)s) << 16;
  return __builtin_bit_cast(float, u);
}

__device__ __forceinline__ unsigned cvt_pk_bf16(float lo, float hi){
  unsigned r;
  asm("v_cvt_pk_bf16_f32 %0, %1, %2" : "=v"(r) : "v"(lo), "v"(hi));
  return r;
}

// ---- small precompute: embi/embjT/alpha (24 blocks) + wg repack (180) ----
__global__ __launch_bounds__(256) void pre_all_kernel(
    const float* __restrict__ emb,
    const float* __restrict__ w1, const float* __restrict__ b1,
    const float* __restrict__ har,
    const float* __restrict__ fc, const float* __restrict__ fg,
    float* __restrict__ wsf){
  const int blk = blockIdx.x;
  const int tid = threadIdx.x;

  if (blk < 24){
    const int gidx = blk*256 + tid;
    const int n = gidx >> 6;
    const int t = gidx & 63;
    const int which = t >> 5, idx = t & 31;
    const float* e = emb + n * D_EMB;
    if (which == 0){
      float acc = b1[idx];
      #pragma unroll
      for (int u = 0; u < D_EMB; u++) acc = fmaf(e[u], w1[(2+u)*H_MLP + idx], acc);
      wsf[WS_F_EMBI + n*H_MLP + idx] = acc;
    } else {
      float acc = 0.f;
      #pragma unroll
      for (int u = 0; u < D_EMB; u++) acc = fmaf(e[u], w1[(2+D_EMB+u)*H_MLP + idx], acc);
      wsf[WS_F_EMBJT + idx*97 + n] = acc;
    }
    if (t == 0){
      float h = har[n];
      float sp = (h > 20.f) ? h : log1pf(expf(h));
      wsf[WS_F_ALPHA + n] = sp + 0.01f;
    }
  } else {
    int idx = (blk - 24) * 256 + tid;
    if (idx < 5 * NPAIR){
      float g = 1.f / (1.f + expf(-fg[idx]));
      float v = fc[idx] * g;
      int f = idx / NPAIR;
      int p = idx - f * NPAIR;
      if (f < 4) wsf[WS_F_WG4 + 4*p + f] = v;
      else       wsf[WS_F_WG1 + p] = v;
    }
  }
}

// Quad numpy-einsum-exact score: rows A,B x columns j1,j2, shared q
// (LDS-broadcast) and per-column kT loads. Each of the 4 chains is
// byte-identical to the proven single np_score rounding sequence. DO NOT TOUCH.
__device__ __forceinline__ void np_score4(const float* __restrict__ qA,
                                          const float* __restrict__ qB,
                                          const float* kT, int j1, int j2,
                                          float* v0A, float* v0B,
                                          float* v1A, float* v1B){
  float A1[4], B1[4], A2[4], B2[4];
  #pragma unroll
  for (int l = 0; l < 4; l++){
    float k1v[8], k2v[8], qa[8], qb[8];
    #pragma unroll
    for (int m = 0; m < 8; m++){
      k1v[m] = kT[(4*m+l)*97 + j1];
      k2v[m] = kT[(4*m+l)*97 + j2];
      qa[m]  = qA[4*m+l];
      qb[m]  = qB[4*m+l];
    }
    float tA1 = __fadd_rn(__fmul_rn(qa[1],k1v[1]), __fmul_rn(qa[0],k1v[0]));
    float tB1 = __fadd_rn(__fmul_rn(qb[1],k1v[1]), __fmul_rn(qb[0],k1v[0]));
    float tA2 = __fadd_rn(__fmul_rn(qa[1],k2v[1]), __fmul_rn(qa[0],k2v[0]));
    float tB2 = __fadd_rn(__fmul_rn(qb[1],k2v[1]), __fmul_rn(qb[0],k2v[0]));
    #pragma unroll
    for (int m = 2; m < 8; m++){
      tA1 = __fadd_rn(__fmul_rn(qa[m],k1v[m]), tA1);
      tB1 = __fadd_rn(__fmul_rn(qb[m],k1v[m]), tB1);
      tA2 = __fadd_rn(__fmul_rn(qa[m],k2v[m]), tA2);
      tB2 = __fadd_rn(__fmul_rn(qb[m],k2v[m]), tB2);
    }
    A1[l]=tA1; B1[l]=tB1; A2[l]=tA2; B2[l]=tB2;
  }
  const float S = 5.65685424949238019521f;
  *v0A = __fdiv_rn(__fadd_rn(__fadd_rn(A1[0],A1[1]), __fadd_rn(A1[2],A1[3])), S);
  *v0B = __fdiv_rn(__fadd_rn(__fadd_rn(B1[0],B1[1]), __fadd_rn(B1[2],B1[3])), S);
  *v1A = __fdiv_rn(__fadd_rn(__fadd_rn(A2[0],A2[1]), __fadd_rn(A2[2],A2[3])), S);
  *v1B = __fdiv_rn(__fadd_rn(__fadd_rn(B2[0],B2[1]), __fadd_rn(B2[2],B2[3])), S);
}

// ---- main (256 threads, 16 rows, 6 blocks per bt): q/kT computed IN-BLOCK
// (bit-exact chains; kills the preqk stage + its kT global round-trip);
// kT f32 + embjT bf16 in LDS; per pair: quad scores -> dual radix top-8 ->
// gather -> 16-pair MFMA per row -> msgs -> softmax.
__global__ __launch_bounds__(256) void main_kernel(
    const float* __restrict__ state, const float* __restrict__ rvec,
    const float* __restrict__ emb,
    const float* __restrict__ qwg, const float* __restrict__ qbg,
    const float* __restrict__ kwg, const float* __restrict__ kbg,
    const float* __restrict__ w2g, const float* __restrict__ b3g,
    const float* __restrict__ w1, const float* __restrict__ b2g,
    const float* __restrict__ w3g,
    const float* __restrict__ wsf,
    float* __restrict__ out_lr, float* __restrict__ out_attn){

  __shared__ float s_kT[3104];                     // 12.4 KB f32 (bit-exact)
  __shared__ __align__(16) float s_q[BROWS*D_EMB]; // 2 KB (own rows)
  __shared__ unsigned short s_embjT16[3104];       // 6.2 KB bf16 (msgs path)
  __shared__ __align__(16) float s_embi[BROWS*H_MLP];  // 2 KB
  __shared__ float s_x[N_SP], s_hol[N_SP];
  __shared__ float s_wxi[H_MLP], s_wxj[H_MLP], s_b2[H_MLP], s_w3[H_MLP];
  __shared__ int   s_selj[4][2][16];
  __shared__ float s_msg[4][2][16];

  const int tid  = threadIdx.x;
  const int bt   = blockIdx.x / 6;
  const int roff = (blockIdx.x - 6*bt) * BROWS;
  const int wave = tid >> 6, lane = tid & 63;

  // kT for ALL n (bit-exact chain: mul, ascending fma, add bias)
  for (int t = tid; t < N_SP*D_EMB; t += 256){
    const int n = t >> 5, d2 = t & 31;
    const float xn = state[bt*N_SP + n];
    const float* e = emb + n*D_EMB;
    float ak = __fmul_rn(xn, kwg[d2]);
    #pragma unroll
    for (int u = 0; u < D_EMB; u++)
      ak = fmaf(e[u], kwg[(1+u)*D_EMB + d2], ak);
    ak = __fadd_rn(ak, kbg[d2]);
    s_kT[d2*97 + n] = ak;
  }
  // q for own 16 rows (bit-exact chain)
  for (int t = tid; t < BROWS*D_EMB; t += 256){
    const int nl = t >> 5, d2 = t & 31;
    const int n  = roff + nl;
    const float xn = state[bt*N_SP + n];
    const float* e = emb + n*D_EMB;
    float aq = __fmul_rn(xn, qwg[d2]);
    #pragma unroll
    for (int u = 0; u < D_EMB; u++)
      aq = fmaf(e[u], qwg[(1+u)*D_EMB + d2], aq);
    aq = __fadd_rn(aq, qbg[d2]);
    s_q[nl*D_EMB + d2] = aq;
  }
  for (int t = tid; t < 3104; t += 256)
    s_embjT16[t] = f2bf(wsf[WS_F_EMBJT + t]);
  for (int t = tid; t < BROWS*H_MLP; t += 256)
    s_embi[t] = wsf[WS_F_EMBI + roff*H_MLP + t];
  if (tid < N_SP){
    float x = state[bt*N_SP + tid];
    s_x[tid] = x;
    float al = wsf[WS_F_ALPHA + tid];
    s_hol[tid] = x / (1.f + al * x);
  }
  if (tid >= 96 && tid < 128){
    int u = tid - 96;
    s_wxi[u] = w1[u];
    s_wxj[u] = w1[H_MLP + u];
    s_b2[u]  = b2g[u];
    s_w3[u]  = w3g[u];
  }

  const float b3v = b3g[0];
  const float* wg4 = wsf + WS_F_WG4;
  const float* wg1 = wsf + WS_F_WG1;

  // w2^T MFMA A-fragments (register-resident)
  const int l15 = lane & 15;
  const int g16 = lane >> 4;
  const int kb  = g16 * 8;
  bf16x8 w2f0, w2f1;
  #pragma unroll
  for (int e = 0; e < 8; e++){
    w2f0[e] = (short)f2bf(w2g[(kb+e)*H_MLP + l15]);
    w2f1[e] = (short)f2bf(w2g[(kb+e)*H_MLP + 16 + l15]);
  }
  __syncthreads();

  const float LOG2E = 1.44269504088896340736f;
  const int j2 = (lane < 32) ? (64 + lane) : 95;   // clamped; lanes>=32 discarded

  for (int ir = 0; ir < 2; ir++){
    const int ilA = 4*wave + 2*ir, ilB = ilA + 1;
    const int iA  = roff + ilA,    iB  = roff + ilB;
    const int ilAu = __builtin_amdgcn_readfirstlane(ilA);
    const int ilBu = __builtin_amdgcn_readfirstlane(ilB);
    const float* qA = s_q + ilAu*D_EMB;   // uniform -> LDS broadcast reads
    const float* qB = s_q + ilBu*D_EMB;

    float v0A, v0B, v1A, v1B;
    np_score4(qA, qB, s_kT, lane, j2, &v0A, &v0B, &v1A, &v1B);

    unsigned k0A = __builtin_bit_cast(unsigned, v0A);
    k0A = (k0A >> 31) ? ~k0A : (k0A | 0x80000000u);
    unsigned k0B = __builtin_bit_cast(unsigned, v0B);
    k0B = (k0B >> 31) ? ~k0B : (k0B | 0x80000000u);
    unsigned k1A = 0u, k1B = 0u;
    if (lane < 32){
      unsigned uA = __builtin_bit_cast(unsigned, v1A);
      k1A = (uA >> 31) ? ~uA : (uA | 0x80000000u);
      unsigned uB = __builtin_bit_cast(unsigned, v1B);
      k1B = (uB >> 31) ? ~uB : (uB | 0x80000000u);
    }

    // dual exact 8th-largest key
    unsigned TA = 0u, TB = 0u;
    #pragma unroll
    for (int b = 31; b >= 0; --b){
      const unsigned bit = 1u << b;
      unsigned TcA = TA | bit;
      unsigned TcB = TB | bit;
      unsigned long long a0 = __ballot(k0A >= TcA);
      unsigned long long b0 = __ballot(k0B >= TcB);
      unsigned long long a1 = __ballot(k1A >= TcA);
      unsigned long long b1 = __ballot(k1B >= TcB);
      if (__popcll(a0) + __popcll(a1) >= 8) TA = TcA;
      if (__popcll(b0) + __popcll(b1) >= 8) TB = TcB;
    }

    // gather selected j's
    unsigned long long mA0 = __ballot(k0A >= TA);
    unsigned long long mA1 = __ballot(k1A >= TA);
    unsigned long long mB0 = __ballot(k0B >= TB);
    unsigned long long mB1 = __ballot(k1B >= TB);
    const int cA0 = __popcll(mA0);
    const int cB0 = __popcll(mB0);
    int r0A = -1, r1A = -1, r0B = -1, r1B = -1;
    const unsigned long long ltm = (1ull << lane) - 1ull;
    if (k0A >= TA){
      r0A = __popcll(mA0 & ltm);
      if (r0A < 16) s_selj[wave][0][r0A] = lane;
    }
    if (lane < 32 && k1A >= TA){
      r1A = cA0 + __popcll(mA1 & ltm);
      if (r1A < 16) s_selj[wave][0][r1A] = 64 + lane;
    }
    if (k0B >= TB){
      r0B = __popcll(mB0 & ltm);
      if (r0B < 16) s_selj[wave][1][r0B] = lane;
    }
    if (lane < 32 && k1B >= TB){
      r1B = cB0 + __popcll(mB1 & ltm);
      if (r1B < 16) s_selj[wave][1][r1B] = 64 + lane;
    }
    asm volatile("s_waitcnt lgkmcnt(0)" ::: "memory");

    const int cntA = cA0 + __popcll(mA1);
    const int cntB = cB0 + __popcll(mB1);
    const int ncapA = (cntA < 16) ? cntA : 16;
    const int ncapB = (cntB < 16) ? cntB : 16;
    const int jPA = s_selj[wave][0][(l15 < ncapA) ? l15 : 0];
    const int jPB = s_selj[wave][1][(l15 < ncapB) ? l15 : 0];
    const float xjA = s_x[jPA], xjB = s_x[jPB];
    const float xiA = s_x[iA],  xiB = s_x[iB];

    float4 w4vA = {0,0,0,0}, w4vB = {0,0,0,0};
    float  w1vA = 0.f, w1vB = 0.f, hjpA = 0.f, hjpB = 0.f;
    if (lane < 16){
      const int pA = iA*N_SP + jPA;
      const int pB = iB*N_SP + jPB;
      w4vA = *(const float4*)&wg4[4*pA];
      w1vA = wg1[pA];
      hjpA = s_hol[jPA];
      w4vB = *(const float4*)&wg4[4*pB];
      w1vB = wg1[pB];
      hjpB = s_hol[jPB];
    }

    u32x4 hwA, hwB;
    #pragma unroll
    for (int e2 = 0; e2 < 4; e2++){
      const int u0 = kb + 2*e2, u1 = u0 + 1;
      const float wj0 = s_wxj[u0], wj1 = s_wxj[u1];
      const float bA0 = fmaf(xiA, s_wxi[u0], s_embi[ilA*H_MLP + u0]);
      const float bA1 = fmaf(xiA, s_wxi[u1], s_embi[ilA*H_MLP + u1]);
      const float bB0 = fmaf(xiB, s_wxi[u0], s_embi[ilB*H_MLP + u0]);
      const float bB1 = fmaf(xiB, s_wxi[u1], s_embi[ilB*H_MLP + u1]);
      float pA0 = gelu_fast(fmaf(xjA, wj0, bA0 + bf2f(s_embjT16[u0*97 + jPA])));
      float pA1 = gelu_fast(fmaf(xjA, wj1, bA1 + bf2f(s_embjT16[u1*97 + jPA])));
      float pB0 = gelu_fast(fmaf(xjB, wj0, bB0 + bf2f(s_embjT16[u0*97 + jPB])));
      float pB1 = gelu_fast(fmaf(xjB, wj1, bB1 + bf2f(s_embjT16[u1*97 + jPB])));
      hwA[e2] = cvt_pk_bf16(pA0, pA1);
      hwB[e2] = cvt_pk_bf16(pB0, pB1);
    }
    const bf16x8 hfA = __builtin_bit_cast(bf16x8, hwA);
    const bf16x8 hfB = __builtin_bit_cast(bf16x8, hwB);

    f32x4 a0A = {s_b2[4*g16+0], s_b2[4*g16+1], s_b2[4*g16+2], s_b2[4*g16+3]};
    f32x4 a1A = {s_b2[16+4*g16+0], s_b2[16+4*g16+1], s_b2[16+4*g16+2], s_b2[16+4*g16+3]};
    f32x4 a0B = a0A, a1B = a1A;
    a0A = __builtin_amdgcn_mfma_f32_16x16x32_bf16(w2f0, hfA, a0A, 0, 0, 0);
    a0B = __builtin_amdgcn_mfma_f32_16x16x32_bf16(w2f0, hfB, a0B, 0, 0, 0);
    a1A = __builtin_amdgcn_mfma_f32_16x16x32_bf16(w2f1, hfA, a1A, 0, 0, 0);
    a1B = __builtin_amdgcn_mfma_f32_16x16x32_bf16(w2f1, hfB, a1B, 0, 0, 0);

    float partA = 0.f, partB = 0.f;
    #pragma unroll
    for (int r = 0; r < 4; r++){
      const float w3v = s_w3[4*g16 + r];
      partA = fmaf(gelu_fast(a0A[r]), w3v, partA);
      partB = fmaf(gelu_fast(a0B[r]), w3v, partB);
    }
    #pragma unroll
    for (int r = 0; r < 4; r++){
      const float w3v = s_w3[16 + 4*g16 + r];
      partA = fmaf(gelu_fast(a1A[r]), w3v, partA);
      partB = fmaf(gelu_fast(a1B[r]), w3v, partB);
    }
    partA += __shfl_xor(partA, 16);
    partB += __shfl_xor(partB, 16);
    partA += __shfl_xor(partA, 32);
    partB += __shfl_xor(partB, 32);

    if (lane < 16){
      const float f4A = partA + b3v;
      const float f4B = partB + b3v;
      const float msgA = w4vA.x * xjA + w4vA.y * (xiA*xjA)
                       + w4vA.z * hjpA + w4vA.w * (xiA*hjpA) + w1vA * f4A;
      const float msgB = w4vB.x * xjB + w4vB.y * (xiB*xjB)
                       + w4vB.z * hjpB + w4vB.w * (xiB*hjpB) + w1vB * f4B;
      s_msg[wave][0][lane] = msgA;
      s_msg[wave][1][lane] = msgB;
    }
    asm volatile("s_waitcnt lgkmcnt(0)" ::: "memory");

    float e0A = (k0A >= TA) ? __builtin_amdgcn_exp2f(LOG2E*v0A) : 0.f;
    float e0B = (k0B >= TB) ? __builtin_amdgcn_exp2f(LOG2E*v0B) : 0.f;
    float e1A = 0.f, e1B = 0.f;
    if (lane < 32){
      if (k1A >= TA) e1A = __builtin_amdgcn_exp2f(LOG2E*v1A);
      if (k1B >= TB) e1B = __builtin_amdgcn_exp2f(LOG2E*v1B);
    }

    float m0A = (r0A >= 0 && r0A < 16) ? s_msg[wave][0][r0A] : 0.f;
    float m1A = (r1A >= 0 && r1A < 16) ? s_msg[wave][0][r1A] : 0.f;
    float m0B = (r0B >= 0 && r0B < 16) ? s_msg[wave][1][r0B] : 0.f;
    float m1B = (r1B >= 0 && r1B < 16) ? s_msg[wave][1][r1B] : 0.f;

    float numA = e0A * m0A;
    float numB = e0B * m0B;
    if (lane < 32){ numA += e1A * m1A; numB += e1B * m1B; }
    float denA = e0A + e1A;
    float denB = e0B + e1B;
    #pragma unroll
    for (int off = 32; off; off >>= 1){
      denA += __shfl_xor(denA, off);
      denB += __shfl_xor(denB, off);
      numA += __shfl_xor(numA, off);
      numB += __shfl_xor(numB, off);
    }
    float invA = 1.0f / denA;
    float invB = 1.0f / denB;
    float* arowA = out_attn + (size_t)(bt*N_SP + iA) * N_SP;
    float* arowB = out_attn + (size_t)(bt*N_SP + iB) * N_SP;
    arowA[lane] = e0A * invA;
    arowB[lane] = e0B * invB;
    if (lane < 32){
      arowA[64 + lane] = e1A * invA;
      arowB[64 + lane] = e1B * invB;
    }
    if (lane == 0){
      out_lr[bt*N_SP + iA] = rvec[iA] + numA * invA;
      out_lr[bt*N_SP + iB] = rvec[iB] + numB * invB;
    }
  }
}

extern "C" void kernel_launch(void* const* d_in, const int* in_sizes, int n_in,
                              void* d_out, int out_size, void* d_ws, size_t ws_size,
                              hipStream_t stream){
  const float* state = (const float*)d_in[0];
  const float* emb   = (const float*)d_in[1];
  const float* qw    = (const float*)d_in[2];
  const float* qb    = (const float*)d_in[3];
  const float* kw    = (const float*)d_in[4];
  const float* kb    = (const float*)d_in[5];
  const float* fc    = (const float*)d_in[6];
  const float* fg    = (const float*)d_in[7];
  const float* har   = (const float*)d_in[8];
  const float* w1    = (const float*)d_in[9];
  const float* b1    = (const float*)d_in[10];
  const float* w2    = (const float*)d_in[11];
  const float* b2    = (const float*)d_in[12];
  const float* w3    = (const float*)d_in[13];
  const float* b3    = (const float*)d_in[14];
  const float* rv    = (const float*)d_in[15];

  float* wsf = (float*)d_ws;
  float* out_lr   = (float*)d_out;
  float* out_attn = out_lr + NBT * N_SP;

  hipLaunchKernelGGL(pre_all_kernel, dim3(24 + 180), dim3(256), 0, stream,
                     emb, w1, b1, har, fc, fg, wsf);
  hipLaunchKernelGGL(main_kernel, dim3(6*NBT), dim3(256), 0, stream,
                     state, rv, emb, qw, qb, kw, kb, w2, b3, w1, b2, w3,
                     wsf, out_lr, out_attn);
}

// Round 25
// 94.657 us; speedup vs baseline: 1.1949x; 1.1949x over previous
//
#include <hip/hip_runtime.h>
#include <math.h>

// Problem constants
#define N_SP 96      // NV + NH
#define D_EMB 32
#define H_MLP 32
#define NPAIR 9216   // N*N
#define NBT 512      // B*T
#define BROWS 16     // rows per block (main: 6 blocks per (b,t))

// float workspace offsets (floats)
#define WS_F_EMBI  0         // 96*32 (includes +b1)
#define WS_F_EMBJT 3072      // 32*97 (transposed [u][j], row stride 97)
#define WS_F_ALPHA 6176      // 96
#define WS_F_WG4   6272      // 9216*4
#define WS_F_WG1   43136     // 9216
#define WS_F_QG    52352     // 512*96*32  q (exact)
#define WS_F_KTG   1625216   // 512*3104   kT stride-97 (exact)
#define WS_F_END   3214464

typedef __attribute__((ext_vector_type(8))) short bf16x8;
typedef __attribute__((ext_vector_type(4))) float f32x4;
typedef __attribute__((ext_vector_type(4))) unsigned u32x4;

__device__ __forceinline__ float gelu_fast(float x){
  float x2 = x * x;
  float z  = x * fmaf(x2, -0.1029438824f, -2.3022077325f);
  float e  = __builtin_amdgcn_exp2f(z);
  return x * __builtin_amdgcn_rcpf(1.0f + e);
}

__device__ __forceinline__ unsigned short f2bf(float f){
  unsigned u = __builtin_bit_cast(unsigned, f);
  unsigned r = (u + 0x7FFFu + ((u >> 16) & 1u)) >> 16;
  return (unsigned short)r;
}
__device__ __forceinline__ float bf2f(unsigned short s){
  unsigned u = ((unsigned)s) << 16;
  return __builtin_bit_cast(float, u);
}

__device__ __forceinline__ unsigned cvt_pk_bf16(float lo, float hi){
  unsigned r;
  asm("v_cvt_pk_bf16_f32 %0, %1, %2" : "=v"(r) : "v"(lo), "v"(hi));
  return r;
}

// ---- fused precompute ----
// blocks [0,1024): per-(bt,half) q/kT, 48 rows each, DIRECT global loads.
//   Op order byte-identical: mul(x,w0), 32x fma ascending, add bias.
// blocks [1024,1048): embi/embjT/alpha.  blocks [1048,1228): wg repack.
__global__ __launch_bounds__(256) void pre_all_kernel(
    const float* __restrict__ state,
    const float* __restrict__ emb,
    const float* __restrict__ qwg, const float* __restrict__ qbg,
    const float* __restrict__ kwg, const float* __restrict__ kbg,
    const float* __restrict__ w1, const float* __restrict__ b1,
    const float* __restrict__ har,
    const float* __restrict__ fc, const float* __restrict__ fg,
    float* __restrict__ wsf){
  const int blk = blockIdx.x;
  const int tid = threadIdx.x;

  if (blk < 2*NBT){
    const int bt   = blk >> 1;
    const int noff = (blk & 1) * 48;
    float* qg  = wsf + WS_F_QG  + bt*(N_SP*D_EMB);
    float* ktg = wsf + WS_F_KTG + bt*3104;
    for (int t = tid; t < 48*D_EMB; t += 256){
      const int n = noff + (t >> 5), d2 = t & 31;
      const float xn = state[bt*N_SP + n];
      const float* e = emb + n*D_EMB;
      float aq = __fmul_rn(xn, qwg[d2]);
      float ak = __fmul_rn(xn, kwg[d2]);
      #pragma unroll
      for (int u = 0; u < D_EMB; u++){
        aq = fmaf(e[u], qwg[(1+u)*D_EMB + d2], aq);
        ak = fmaf(e[u], kwg[(1+u)*D_EMB + d2], ak);
      }
      aq = __fadd_rn(aq, qbg[d2]);
      ak = __fadd_rn(ak, kbg[d2]);
      qg[n*D_EMB + d2] = aq;
      ktg[d2*97 + n]   = ak;
    }
  } else if (blk < 2*NBT + 24){
    const int gidx = (blk - 2*NBT)*256 + tid;
    const int n = gidx >> 6;
    const int t = gidx & 63;
    const int which = t >> 5, idx = t & 31;
    const float* e = emb + n * D_EMB;
    if (which == 0){
      float acc = b1[idx];
      #pragma unroll
      for (int u = 0; u < D_EMB; u++) acc = fmaf(e[u], w1[(2+u)*H_MLP + idx], acc);
      wsf[WS_F_EMBI + n*H_MLP + idx] = acc;
    } else {
      float acc = 0.f;
      #pragma unroll
      for (int u = 0; u < D_EMB; u++) acc = fmaf(e[u], w1[(2+D_EMB+u)*H_MLP + idx], acc);
      wsf[WS_F_EMBJT + idx*97 + n] = acc;
    }
    if (t == 0){
      float h = har[n];
      float sp = (h > 20.f) ? h : log1pf(expf(h));
      wsf[WS_F_ALPHA + n] = sp + 0.01f;
    }
  } else {
    int idx = (blk - 2*NBT - 24) * 256 + tid;
    if (idx < 5 * NPAIR){
      float g = 1.f / (1.f + expf(-fg[idx]));
      float v = fc[idx] * g;
      int f = idx / NPAIR;
      int p = idx - f * NPAIR;
      if (f < 4) wsf[WS_F_WG4 + 4*p + f] = v;
      else       wsf[WS_F_WG1 + p] = v;
    }
  }
}

// Quad numpy-einsum-exact score: rows A,B x columns j1,j2, shared q (scalar)
// and per-column kT loads. Each of the 4 chains is byte-identical to the
// proven single np_score rounding sequence. DO NOT TOUCH.
__device__ __forceinline__ void np_score4(const float* __restrict__ qA,
                                          const float* __restrict__ qB,
                                          const float* kT, int j1, int j2,
                                          float* v0A, float* v0B,
                                          float* v1A, float* v1B){
  float A1[4], B1[4], A2[4], B2[4];
  #pragma unroll
  for (int l = 0; l < 4; l++){
    float k1v[8], k2v[8], qa[8], qb[8];
    #pragma unroll
    for (int m = 0; m < 8; m++){
      k1v[m] = kT[(4*m+l)*97 + j1];
      k2v[m] = kT[(4*m+l)*97 + j2];
      qa[m]  = qA[4*m+l];
      qb[m]  = qB[4*m+l];
    }
    float tA1 = __fadd_rn(__fmul_rn(qa[1],k1v[1]), __fmul_rn(qa[0],k1v[0]));
    float tB1 = __fadd_rn(__fmul_rn(qb[1],k1v[1]), __fmul_rn(qb[0],k1v[0]));
    float tA2 = __fadd_rn(__fmul_rn(qa[1],k2v[1]), __fmul_rn(qa[0],k2v[0]));
    float tB2 = __fadd_rn(__fmul_rn(qb[1],k2v[1]), __fmul_rn(qb[0],k2v[0]));
    #pragma unroll
    for (int m = 2; m < 8; m++){
      tA1 = __fadd_rn(__fmul_rn(qa[m],k1v[m]), tA1);
      tB1 = __fadd_rn(__fmul_rn(qb[m],k1v[m]), tB1);
      tA2 = __fadd_rn(__fmul_rn(qa[m],k2v[m]), tA2);
      tB2 = __fadd_rn(__fmul_rn(qb[m],k2v[m]), tB2);
    }
    A1[l]=tA1; B1[l]=tB1; A2[l]=tA2; B2[l]=tB2;
  }
  const float S = 5.65685424949238019521f;
  *v0A = __fdiv_rn(__fadd_rn(__fadd_rn(A1[0],A1[1]), __fadd_rn(A1[2],A1[3])), S);
  *v0B = __fdiv_rn(__fadd_rn(__fadd_rn(B1[0],B1[1]), __fadd_rn(B1[2],B1[3])), S);
  *v1A = __fdiv_rn(__fadd_rn(__fadd_rn(A2[0],A2[1]), __fadd_rn(A2[2],A2[3])), S);
  *v1B = __fdiv_rn(__fadd_rn(__fadd_rn(B2[0],B2[1]), __fadd_rn(B2[2],B2[3])), S);
}

// ---- main (256 threads, 16 rows, 6 blocks per bt): kT f32 + embjT bf16 in
// LDS (23 KB); q via scalar loads; per pair: quad scores -> dual radix
// top-8 -> gather -> 16-pair MFMA per row -> msgs -> softmax. (R22/R23
// kernel, byte-identical — 77.5-78 us proven.)
__global__ __launch_bounds__(256) void main_kernel(
    const float* __restrict__ state, const float* __restrict__ rvec,
    const float* __restrict__ w2g, const float* __restrict__ b3g,
    const float* __restrict__ w1, const float* __restrict__ b2g,
    const float* __restrict__ w3g,
    const float* __restrict__ wsf,
    float* __restrict__ out_lr, float* __restrict__ out_attn){

  __shared__ float s_kT[3104];                     // 12.4 KB f32 (bit-exact)
  __shared__ unsigned short s_embjT16[3104];       // 6.2 KB bf16 (msgs path)
  __shared__ __align__(16) float s_embi[BROWS*H_MLP];  // 2 KB
  __shared__ float s_x[N_SP], s_hol[N_SP];
  __shared__ float s_wxi[H_MLP], s_wxj[H_MLP], s_b2[H_MLP], s_w3[H_MLP];
  __shared__ int   s_selj[4][2][16];
  __shared__ float s_msg[4][2][16];

  const int tid  = threadIdx.x;
  const int bt   = blockIdx.x / 6;
  const int roff = (blockIdx.x - 6*bt) * BROWS;
  const int wave = tid >> 6, lane = tid & 63;

  const float* ktg = wsf + WS_F_KTG + bt*3104;
  for (int t = tid; t < 3104; t += 256){
    s_kT[t]       = ktg[t];
    s_embjT16[t]  = f2bf(wsf[WS_F_EMBJT + t]);
  }
  for (int t = tid; t < BROWS*H_MLP; t += 256)
    s_embi[t] = wsf[WS_F_EMBI + roff*H_MLP + t];
  if (tid < N_SP){
    float x = state[bt*N_SP + tid];
    s_x[tid] = x;
    float al = wsf[WS_F_ALPHA + tid];
    s_hol[tid] = x / (1.f + al * x);
  }
  if (tid >= 96 && tid < 128){
    int u = tid - 96;
    s_wxi[u] = w1[u];
    s_wxj[u] = w1[H_MLP + u];
    s_b2[u]  = b2g[u];
    s_w3[u]  = w3g[u];
  }

  const float b3v = b3g[0];
  const float* wg4 = wsf + WS_F_WG4;
  const float* wg1 = wsf + WS_F_WG1;
  const float* qg  = wsf + WS_F_QG + bt*(N_SP*D_EMB);

  // w2^T MFMA A-fragments (register-resident)
  const int l15 = lane & 15;
  const int g16 = lane >> 4;
  const int kb  = g16 * 8;
  bf16x8 w2f0, w2f1;
  #pragma unroll
  for (int e = 0; e < 8; e++){
    w2f0[e] = (short)f2bf(w2g[(kb+e)*H_MLP + l15]);
    w2f1[e] = (short)f2bf(w2g[(kb+e)*H_MLP + 16 + l15]);
  }
  __syncthreads();

  const float LOG2E = 1.44269504088896340736f;
  const int j2 = (lane < 32) ? (64 + lane) : 95;   // clamped; lanes>=32 discarded

  for (int ir = 0; ir < 2; ir++){
    const int ilA = 4*wave + 2*ir, ilB = ilA + 1;
    const int iA  = roff + ilA,    iB  = roff + ilB;
    const int iAu = __builtin_amdgcn_readfirstlane(iA);
    const int iBu = __builtin_amdgcn_readfirstlane(iB);
    const float* qA = qg + iAu*D_EMB;
    const float* qB = qg + iBu*D_EMB;

    float v0A, v0B, v1A, v1B;
    np_score4(qA, qB, s_kT, lane, j2, &v0A, &v0B, &v1A, &v1B);

    unsigned k0A = __builtin_bit_cast(unsigned, v0A);
    k0A = (k0A >> 31) ? ~k0A : (k0A | 0x80000000u);
    unsigned k0B = __builtin_bit_cast(unsigned, v0B);
    k0B = (k0B >> 31) ? ~k0B : (k0B | 0x80000000u);
    unsigned k1A = 0u, k1B = 0u;
    if (lane < 32){
      unsigned uA = __builtin_bit_cast(unsigned, v1A);
      k1A = (uA >> 31) ? ~uA : (uA | 0x80000000u);
      unsigned uB = __builtin_bit_cast(unsigned, v1B);
      k1B = (uB >> 31) ? ~uB : (uB | 0x80000000u);
    }

    // dual exact 8th-largest key
    unsigned TA = 0u, TB = 0u;
    #pragma unroll
    for (int b = 31; b >= 0; --b){
      const unsigned bit = 1u << b;
      unsigned TcA = TA | bit;
      unsigned TcB = TB | bit;
      unsigned long long a0 = __ballot(k0A >= TcA);
      unsigned long long b0 = __ballot(k0B >= TcB);
      unsigned long long a1 = __ballot(k1A >= TcA);
      unsigned long long b1 = __ballot(k1B >= TcB);
      if (__popcll(a0) + __popcll(a1) >= 8) TA = TcA;
      if (__popcll(b0) + __popcll(b1) >= 8) TB = TcB;
    }

    // gather selected j's
    unsigned long long mA0 = __ballot(k0A >= TA);
    unsigned long long mA1 = __ballot(k1A >= TA);
    unsigned long long mB0 = __ballot(k0B >= TB);
    unsigned long long mB1 = __ballot(k1B >= TB);
    const int cA0 = __popcll(mA0);
    const int cB0 = __popcll(mB0);
    int r0A = -1, r1A = -1, r0B = -1, r1B = -1;
    const unsigned long long ltm = (1ull << lane) - 1ull;
    if (k0A >= TA){
      r0A = __popcll(mA0 & ltm);
      if (r0A < 16) s_selj[wave][0][r0A] = lane;
    }
    if (lane < 32 && k1A >= TA){
      r1A = cA0 + __popcll(mA1 & ltm);
      if (r1A < 16) s_selj[wave][0][r1A] = 64 + lane;
    }
    if (k0B >= TB){
      r0B = __popcll(mB0 & ltm);
      if (r0B < 16) s_selj[wave][1][r0B] = lane;
    }
    if (lane < 32 && k1B >= TB){
      r1B = cB0 + __popcll(mB1 & ltm);
      if (r1B < 16) s_selj[wave][1][r1B] = 64 + lane;
    }
    asm volatile("s_waitcnt lgkmcnt(0)" ::: "memory");

    const int cntA = cA0 + __popcll(mA1);
    const int cntB = cB0 + __popcll(mB1);
    const int ncapA = (cntA < 16) ? cntA : 16;
    const int ncapB = (cntB < 16) ? cntB : 16;
    const int jPA = s_selj[wave][0][(l15 < ncapA) ? l15 : 0];
    const int jPB = s_selj[wave][1][(l15 < ncapB) ? l15 : 0];
    const float xjA = s_x[jPA], xjB = s_x[jPB];
    const float xiA = s_x[iA],  xiB = s_x[iB];

    float4 w4vA = {0,0,0,0}, w4vB = {0,0,0,0};
    float  w1vA = 0.f, w1vB = 0.f, hjpA = 0.f, hjpB = 0.f;
    if (lane < 16){
      const int pA = iA*N_SP + jPA;
      const int pB = iB*N_SP + jPB;
      w4vA = *(const float4*)&wg4[4*pA];
      w1vA = wg1[pA];
      hjpA = s_hol[jPA];
      w4vB = *(const float4*)&wg4[4*pB];
      w1vB = wg1[pB];
      hjpB = s_hol[jPB];
    }

    u32x4 hwA, hwB;
    #pragma unroll
    for (int e2 = 0; e2 < 4; e2++){
      const int u0 = kb + 2*e2, u1 = u0 + 1;
      const float wj0 = s_wxj[u0], wj1 = s_wxj[u1];
      const float bA0 = fmaf(xiA, s_wxi[u0], s_embi[ilA*H_MLP + u0]);
      const float bA1 = fmaf(xiA, s_wxi[u1], s_embi[ilA*H_MLP + u1]);
      const float bB0 = fmaf(xiB, s_wxi[u0], s_embi[ilB*H_MLP + u0]);
      const float bB1 = fmaf(xiB, s_wxi[u1], s_embi[ilB*H_MLP + u1]);
      float pA0 = gelu_fast(fmaf(xjA, wj0, bA0 + bf2f(s_embjT16[u0*97 + jPA])));
      float pA1 = gelu_fast(fmaf(xjA, wj1, bA1 + bf2f(s_embjT16[u1*97 + jPA])));
      float pB0 = gelu_fast(fmaf(xjB, wj0, bB0 + bf2f(s_embjT16[u0*97 + jPB])));
      float pB1 = gelu_fast(fmaf(xjB, wj1, bB1 + bf2f(s_embjT16[u1*97 + jPB])));
      hwA[e2] = cvt_pk_bf16(pA0, pA1);
      hwB[e2] = cvt_pk_bf16(pB0, pB1);
    }
    const bf16x8 hfA = __builtin_bit_cast(bf16x8, hwA);
    const bf16x8 hfB = __builtin_bit_cast(bf16x8, hwB);

    f32x4 a0A = {s_b2[4*g16+0], s_b2[4*g16+1], s_b2[4*g16+2], s_b2[4*g16+3]};
    f32x4 a1A = {s_b2[16+4*g16+0], s_b2[16+4*g16+1], s_b2[16+4*g16+2], s_b2[16+4*g16+3]};
    f32x4 a0B = a0A, a1B = a1A;
    a0A = __builtin_amdgcn_mfma_f32_16x16x32_bf16(w2f0, hfA, a0A, 0, 0, 0);
    a0B = __builtin_amdgcn_mfma_f32_16x16x32_bf16(w2f0, hfB, a0B, 0, 0, 0);
    a1A = __builtin_amdgcn_mfma_f32_16x16x32_bf16(w2f1, hfA, a1A, 0, 0, 0);
    a1B = __builtin_amdgcn_mfma_f32_16x16x32_bf16(w2f1, hfB, a1B, 0, 0, 0);

    float partA = 0.f, partB = 0.f;
    #pragma unroll
    for (int r = 0; r < 4; r++){
      const float w3v = s_w3[4*g16 + r];
      partA = fmaf(gelu_fast(a0A[r]), w3v, partA);
      partB = fmaf(gelu_fast(a0B[r]), w3v, partB);
    }
    #pragma unroll
    for (int r = 0; r < 4; r++){
      const float w3v = s_w3[16 + 4*g16 + r];
      partA = fmaf(gelu_fast(a1A[r]), w3v, partA);
      partB = fmaf(gelu_fast(a1B[r]), w3v, partB);
    }
    partA += __shfl_xor(partA, 16);
    partB += __shfl_xor(partB, 16);
    partA += __shfl_xor(partA, 32);
    partB += __shfl_xor(partB, 32);

    if (lane < 16){
      const float f4A = partA + b3v;
      const float f4B = partB + b3v;
      const float msgA = w4vA.x * xjA + w4vA.y * (xiA*xjA)
                       + w4vA.z * hjpA + w4vA.w * (xiA*hjpA) + w1vA * f4A;
      const float msgB = w4vB.x * xjB + w4vB.y * (xiB*xjB)
                       + w4vB.z * hjpB + w4vB.w * (xiB*hjpB) + w1vB * f4B;
      s_msg[wave][0][lane] = msgA;
      s_msg[wave][1][lane] = msgB;
    }
    asm volatile("s_waitcnt lgkmcnt(0)" ::: "memory");

    float e0A = (k0A >= TA) ? __builtin_amdgcn_exp2f(LOG2E*v0A) : 0.f;
    float e0B = (k0B >= TB) ? __builtin_amdgcn_exp2f(LOG2E*v0B) : 0.f;
    float e1A = 0.f, e1B = 0.f;
    if (lane < 32){
      if (k1A >= TA) e1A = __builtin_amdgcn_exp2f(LOG2E*v1A);
      if (k1B >= TB) e1B = __builtin_amdgcn_exp2f(LOG2E*v1B);
    }

    float m0A = (r0A >= 0 && r0A < 16) ? s_msg[wave][0][r0A] : 0.f;
    float m1A = (r1A >= 0 && r1A < 16) ? s_msg[wave][0][r1A] : 0.f;
    float m0B = (r0B >= 0 && r0B < 16) ? s_msg[wave][1][r0B] : 0.f;
    float m1B = (r1B >= 0 && r1B < 16) ? s_msg[wave][1][r1B] : 0.f;

    float numA = e0A * m0A;
    float numB = e0B * m0B;
    if (lane < 32){ numA += e1A * m1A; numB += e1B * m1B; }
    float denA = e0A + e1A;
    float denB = e0B + e1B;
    #pragma unroll
    for (int off = 32; off; off >>= 1){
      denA += __shfl_xor(denA, off);
      denB += __shfl_xor(denB, off);
      numA += __shfl_xor(numA, off);
      numB += __shfl_xor(numB, off);
    }
    float invA = 1.0f / denA;
    float invB = 1.0f / denB;
    float* arowA = out_attn + (size_t)(bt*N_SP + iA) * N_SP;
    float* arowB = out_attn + (size_t)(bt*N_SP + iB) * N_SP;
    arowA[lane] = e0A * invA;
    arowB[lane] = e0B * invB;
    if (lane < 32){
      arowA[64 + lane] = e1A * invA;
      arowB[64 + lane] = e1B * invB;
    }
    if (lane == 0){
      out_lr[bt*N_SP + iA] = rvec[iA] + numA * invA;
      out_lr[bt*N_SP + iB] = rvec[iB] + numB * invB;
    }
  }
}

extern "C" void kernel_launch(void* const* d_in, const int* in_sizes, int n_in,
                              void* d_out, int out_size, void* d_ws, size_t ws_size,
                              hipStream_t stream){
  const float* state = (const float*)d_in[0];
  const float* emb   = (const float*)d_in[1];
  const float* qw    = (const float*)d_in[2];
  const float* qb    = (const float*)d_in[3];
  const float* kw    = (const float*)d_in[4];
  const float* kb    = (const float*)d_in[5];
  const float* fc    = (const float*)d_in[6];
  const float* fg    = (const float*)d_in[7];
  const float* har   = (const float*)d_in[8];
  const float* w1    = (const float*)d_in[9];
  const float* b1    = (const float*)d_in[10];
  const float* w2    = (const float*)d_in[11];
  const float* b2    = (const float*)d_in[12];
  const float* w3    = (const float*)d_in[13];
  const float* b3    = (const float*)d_in[14];
  const float* rv    = (const float*)d_in[15];

  float* wsf = (float*)d_ws;
  float* out_lr   = (float*)d_out;
  float* out_attn = out_lr + NBT * N_SP;

  hipLaunchKernelGGL(pre_all_kernel, dim3(2*NBT + 24 + 180), dim3(256), 0, stream,
                     state, emb, qw, qb, kw, kb, w1, b1, har, fc, fg, wsf);
  hipLaunchKernelGGL(main_kernel, dim3(6*NBT), dim3(256), 0, stream,
                     state, rv, w2, b3, w1, b2, w3, wsf, out_lr, out_attn);
}